// Round 1
// baseline (349.294 us; speedup 1.0000x reference)
//
#include <hip/hip_runtime.h>

// N = 33554432 ; inputs: s (int32), other_s (int32), x (float32)
// out = mean( (s==other_s ? 1 : -1) * x )

constexpr int BLOCK = 256;
constexpr int GRID  = 1024;   // 256 CUs * 4 blocks; 32 float4 iters/thread at N=32M

__global__ __launch_bounds__(BLOCK) void disc_loss_partial(
        const int*   __restrict__ s,
        const int*   __restrict__ o,
        const float* __restrict__ x,
        float*       __restrict__ partials,
        int n4)
{
    const int4*   s4 = (const int4*)s;
    const int4*   o4 = (const int4*)o;
    const float4* x4 = (const float4*)x;

    float acc = 0.0f;
    int stride = GRID * BLOCK;
    for (int i = blockIdx.x * BLOCK + threadIdx.x; i < n4; i += stride) {
        int4   sv = s4[i];
        int4   ov = o4[i];
        float4 xv = x4[i];
        acc += (sv.x == ov.x) ? xv.x : -xv.x;
        acc += (sv.y == ov.y) ? xv.y : -xv.y;
        acc += (sv.z == ov.z) ? xv.z : -xv.z;
        acc += (sv.w == ov.w) ? xv.w : -xv.w;
    }

    // wave-64 shuffle reduction
    #pragma unroll
    for (int off = 32; off > 0; off >>= 1)
        acc += __shfl_down(acc, off, 64);

    __shared__ float lds[BLOCK / 64];
    int lane = threadIdx.x & 63;
    int wid  = threadIdx.x >> 6;
    if (lane == 0) lds[wid] = acc;
    __syncthreads();
    if (threadIdx.x == 0) {
        float sum = 0.0f;
        #pragma unroll
        for (int w = 0; w < BLOCK / 64; ++w) sum += lds[w];
        partials[blockIdx.x] = sum;
    }
}

__global__ __launch_bounds__(256) void disc_loss_final(
        const float* __restrict__ partials,
        float*       __restrict__ out,
        float inv_n)
{
    float acc = 0.0f;
    for (int i = threadIdx.x; i < GRID; i += 256)
        acc += partials[i];

    #pragma unroll
    for (int off = 32; off > 0; off >>= 1)
        acc += __shfl_down(acc, off, 64);

    __shared__ float lds[4];
    int lane = threadIdx.x & 63;
    int wid  = threadIdx.x >> 6;
    if (lane == 0) lds[wid] = acc;
    __syncthreads();
    if (threadIdx.x == 0)
        out[0] = (lds[0] + lds[1] + lds[2] + lds[3]) * inv_n;
}

extern "C" void kernel_launch(void* const* d_in, const int* in_sizes, int n_in,
                              void* d_out, int out_size, void* d_ws, size_t ws_size,
                              hipStream_t stream)
{
    const int*   s = (const int*)d_in[0];
    const int*   o = (const int*)d_in[1];
    const float* x = (const float*)d_in[2];
    float* out      = (float*)d_out;
    float* partials = (float*)d_ws;   // GRID floats = 4 KB

    int n  = in_sizes[0];
    int n4 = n / 4;                   // N divisible by 4

    disc_loss_partial<<<GRID, BLOCK, 0, stream>>>(s, o, x, partials, n4);
    disc_loss_final<<<1, 256, 0, stream>>>(partials, out, 1.0f / (float)n);
}